// Round 9
// baseline (80.823 us; speedup 1.0000x reference)
//
#include <hip/hip_runtime.h>

// spikes = (floor(v0 + cumsum(relu(x)*DT)) - floor(prev)) / DT, f64 scan.
// (f32 scan flips floors vs the f64 np reference — R0/R1; f64 segment
// reassociation ~1e-16, validated absmax 0.0 in R3/R4/R6/R7/R8.)
//
// History: R3 fused 16-seg 2x-read = 57.4us; R6 2x wave pool = 57.7us
// (NOT wave-starved; ~7 TB/s aggregate traffic ceiling binding).
// R7 (1024,8): VGPR budget 256/8=32 -> buf[32] spilled hard (244us).
// R8 (1024,4): budget 256/4=64, demand ~72 -> 8-dword spill
//   (WRITE 131->164 MB, 78.5us). LESSON: hipcc budgets VGPRs from the
//   256-entry arch-file model: cap = 256 / waves_per_eu.
// R9 = same kernel with (1024,2): budget 128 >= demand ~72 -> no spill.
//   A 1024-thread block (16 waves, 4/SIMD) still fits: 4 x 128 = 512/SIMD.
//   Traffic 268 MB @ ~7 TB/s aggregate -> ~38us floor.

#pragma clang fp contract(off)   // np rounds rate before accumulating: no FMA

constexpr int B = 16;
constexpr int T = 2048;
constexpr int D = 1024;
constexpr int NSEG = 64;          // segments along T
constexpr int TSEG = T / NSEG;    // 32 steps per segment (register-resident)
constexpr int CPB = 16;           // chains per block
constexpr int SPW = 4;            // segments per wave (64 lanes / 16 chains)

__global__ __launch_bounds__(1024, 2)   // VGPR budget 256/2 = 128: no spill
void spike_scan_kernel(const float* __restrict__ in,
                       const float* __restrict__ state,
                       float* __restrict__ out) {
  const int lane = threadIdx.x & 63;
  const int wave = threadIdx.x >> 6;              // 0..15
  const int sub  = lane & 15;                     // chain within block
  const int seg  = wave * SPW + (lane >> 4);      // segment 0..63

  const int c = blockIdx.x * CPB + sub;           // chain id
  const int b = c >> 10;                          // D = 1024
  const int d = c & (D - 1);
  const size_t base = (size_t)b * T * D + d + (size_t)seg * TSEG * D;
  const float* __restrict__ ip = in + base;
  float* __restrict__ op = out + base;

  __shared__ double segsum[NSEG][CPB];            // 8 KB

  // ---- Load the whole segment into registers (the ONLY input read) ----
  float buf[TSEG];
#pragma unroll
  for (int u = 0; u < TSEG; ++u) buf[u] = ip[(size_t)u * D];

  // ---- Phase 1: in-order f64 segment sum ----
  double ssum = 0.0;
#pragma unroll
  for (int u = 0; u < TSEG; ++u)
    ssum += (double)fmaxf(buf[u], 0.0f) * 0.001;
  segsum[seg][sub] = ssum;
  __syncthreads();

  // ---- Phase 2: in-order prefix over preceding segments, emit from regs ----
  const double v0 = (double)state[c];
  double s = 0.0;
  for (int w = 0; w < seg; ++w) s += segsum[w][sub];
  double prev = floor(v0 + s);                    // seg 0: floor(v0)

#pragma unroll
  for (int u = 0; u < TSEG; ++u) {
    s += (double)fmaxf(buf[u], 0.0f) * 0.001;
    const double fl = floor(v0 + s);
    op[(size_t)u * D] = (float)((fl - prev) * 1000.0);
    prev = fl;
  }
}

extern "C" void kernel_launch(void* const* d_in, const int* in_sizes, int n_in,
                              void* d_out, int out_size, void* d_ws, size_t ws_size,
                              hipStream_t stream) {
  const float* in = (const float*)d_in[0];     // [B, T, D] f32
  const float* st = (const float*)d_in[1];     // [B, D]    f32
  float* out = (float*)d_out;                  // [B, T, D] f32

  // 16384 chains / 16 per block = 1024 blocks x 1024 threads (16 waves).
  dim3 grid(B * D / CPB);
  dim3 block(1024);
  spike_scan_kernel<<<grid, block, 0, stream>>>(in, st, out);
}

// Round 10
// 77.313 us; speedup vs baseline: 1.0454x; 1.0454x over previous
//
#include <hip/hip_runtime.h>

// spikes = (floor(v0 + cumsum(relu(x)*DT)) - floor(prev)) / DT, f64 scan.
// (f32 scan flips floors vs the f64 np reference — R0/R1; f64 segment
// reassociation ~1e-16, validated absmax 0.0 in R3/R4/R6-R9.)
//
// History: R3 fused 16-seg 2x-read = 57.4us; R6 2x wave pool = 57.7us
// (NOT wave-starved; ~7 TB/s aggregate traffic ceiling suspected).
// R7 (1024,8): cap 256/8=32 -> huge spill, 244us.
// R8 (1024,4): cap 64 vs demand ~72 -> 8-dword spill, 78.5us.
// R9 (1024,2): IDENTICAL to R8 — a 1024-thr block is 4 waves/SIMD minimum,
//   so the occupancy request clamps to 4 -> cap stays 256/4=64.
//   LESSON: 1024-thread blocks can never exceed 64 VGPR/thread.
// R10: 512-thread block (2 waves/SIMD min -> cap 128). CPB=16 x NSEG=32,
//   TSEG=64: buf[64]+state+addr ~ 90 regs, no spill. Single input read,
//   traffic 268 MB; floor ~38us at the 7 TB/s aggregate ceiling.

#pragma clang fp contract(off)   // np rounds rate before accumulating: no FMA

constexpr int B = 16;
constexpr int T = 2048;
constexpr int D = 1024;
constexpr int NSEG = 32;          // segments along T
constexpr int TSEG = T / NSEG;    // 64 steps per segment (register-resident)
constexpr int CPB = 16;           // chains per block
constexpr int SPW = 4;            // segment-groups per wave (64 lanes / 16)

__global__ __launch_bounds__(512, 2)    // 8 waves/block; VGPR cap 256/2 = 128
void spike_scan_kernel(const float* __restrict__ in,
                       const float* __restrict__ state,
                       float* __restrict__ out) {
  const int lane = threadIdx.x & 63;
  const int wave = threadIdx.x >> 6;              // 0..7
  const int sub  = lane & 15;                     // chain within block
  const int seg  = wave * SPW + (lane >> 4);      // segment 0..31

  const int c = blockIdx.x * CPB + sub;           // chain id
  const int b = c >> 10;                          // D = 1024
  const int d = c & (D - 1);
  const size_t base = (size_t)b * T * D + d + (size_t)seg * TSEG * D;
  const float* __restrict__ ip = in + base;
  float* __restrict__ op = out + base;

  __shared__ double segsum[NSEG][CPB];            // 4 KB

  // ---- Load the whole segment into registers (the ONLY input read) ----
  float buf[TSEG];
#pragma unroll
  for (int u = 0; u < TSEG; ++u) buf[u] = ip[(size_t)u * D];

  // ---- Phase 1: in-order f64 segment sum ----
  double ssum = 0.0;
#pragma unroll
  for (int u = 0; u < TSEG; ++u)
    ssum += (double)fmaxf(buf[u], 0.0f) * 0.001;
  segsum[seg][sub] = ssum;
  __syncthreads();

  // ---- Phase 2: in-order prefix over preceding segments, emit from regs ----
  const double v0 = (double)state[c];
  double s = 0.0;
  for (int w = 0; w < seg; ++w) s += segsum[w][sub];
  double prev = floor(v0 + s);                    // seg 0: floor(v0)

#pragma unroll
  for (int u = 0; u < TSEG; ++u) {
    s += (double)fmaxf(buf[u], 0.0f) * 0.001;
    const double fl = floor(v0 + s);
    op[(size_t)u * D] = (float)((fl - prev) * 1000.0);
    prev = fl;
  }
}

extern "C" void kernel_launch(void* const* d_in, const int* in_sizes, int n_in,
                              void* d_out, int out_size, void* d_ws, size_t ws_size,
                              hipStream_t stream) {
  const float* in = (const float*)d_in[0];     // [B, T, D] f32
  const float* st = (const float*)d_in[1];     // [B, D]    f32
  float* out = (float*)d_out;                  // [B, T, D] f32

  // 16384 chains / 16 per block = 1024 blocks x 512 threads (8 waves).
  dim3 grid(B * D / CPB);
  dim3 block(512);
  spike_scan_kernel<<<grid, block, 0, stream>>>(in, st, out);
}

// Round 11
// 39.473 us; speedup vs baseline: 2.0475x; 1.9586x over previous
//
#include <hip/hip_runtime.h>

// spikes = (floor(v0 + cumsum(relu(x)*DT)) - floor(prev)) / DT, f64 scan.
// (f32 scan flips floors vs f64 np reference — R0/R1. f64 segment
// reassociation ~1e-16: validated absmax 0.0 in R3-R10.)
//
// History: R3 2x-read coalesced = 57.4us (7.0 TB/s aggregate). R10 1x-read
// register-resident but 64B-granular (16-chain groups) = 77us @ 3.5 TB/s.
// LESSON: need single-read AND 256B coalescing simultaneously.
// R11: block = 64 chains (lane=chain, 256B coalesced) x 16 waves. T in 16
// tiles of 128 rows; wave w owns 8 rows/tile, held in REGISTERS (8 f32).
// Cross-wave combine via 16KB LDS segsum only. Raw s_barrier + lgkmcnt(0)
// per tile (NOT __syncthreads — its vmcnt(0) drain kills the reg prefetch
// pipeline). Single HBM read: 268 MB total, all 256B accesses.

#pragma clang fp contract(off)   // np rounds rate before accumulating: no FMA

constexpr int B = 16;
constexpr int T = 2048;
constexpr int D = 1024;
constexpr int CPB = 64;           // chains per block (lane = chain)
constexpr int NW  = 16;           // waves per block
constexpr int RPW = 8;            // rows per wave per tile (reg-resident)
constexpr int TT  = NW * RPW;     // 128 t-steps per tile
constexpr int NTILE = T / TT;     // 16 tiles

__global__ __launch_bounds__(1024, 4)   // cap 64 VGPR; demand ~50: no spill
void spike_scan_kernel(const float* __restrict__ in,
                       const float* __restrict__ state,
                       float* __restrict__ out) {
  const int lane = threadIdx.x & 63;
  const int wave = threadIdx.x >> 6;              // 0..15
  const int c = blockIdx.x * CPB + lane;          // chain id
  const int b = c >> 10;                          // D = 1024; 64|1024
  const int d = c & (D - 1);
  // Point at this wave's row 0 of tile 0; tile k adds k*TT*D.
  const float* __restrict__ ip =
      in + (size_t)b * T * D + d + (size_t)wave * RPW * D;
  float* __restrict__ op =
      out + (size_t)b * T * D + d + (size_t)wave * RPW * D;

  __shared__ double segsum[2][NW][CPB];           // 16 KB, double-buffered

  const double v0 = (double)state[c];
  double sbase = 0.0;                             // chain cumsum before tile k

  float bufA[RPW], bufB[RPW];
#pragma unroll
  for (int r = 0; r < RPW; ++r) bufA[r] = ip[(size_t)r * D];   // tile 0

  auto tile = [&](int k, float (&cur)[RPW], float (&nxt)[RPW]) {
    // Prefetch next tile's own rows into the spare reg buffer (coalesced).
    if (k + 1 < NTILE) {
      const float* p = ip + (size_t)(k + 1) * TT * D;
#pragma unroll
      for (int r = 0; r < RPW; ++r) nxt[r] = p[(size_t)r * D];
    }
    // In-order f64 sum of this wave's 8-row sub-segment.
    double ss = 0.0;
#pragma unroll
    for (int r = 0; r < RPW; ++r)
      ss += (double)fmaxf(cur[r], 0.0f) * 0.001;
    segsum[k & 1][wave][lane] = ss;
    asm volatile("s_waitcnt lgkmcnt(0)" ::: "memory");  // segsum visible
    __builtin_amdgcn_s_barrier();                       // no vmcnt drain!
    asm volatile("" ::: "memory");
    // In-order prefix: mypre = sum of waves < me; acc = all 16 (for sbase).
    double acc = 0.0, mypre = 0.0;
#pragma unroll
    for (int w = 0; w < NW; ++w) {
      if (w == wave) mypre = acc;
      acc += segsum[k & 1][w][lane];
    }
    // Emit this sub-segment from registers (coalesced 256B stores).
    double s = sbase + mypre;
    double prev = floor(v0 + s);                  // k=0,w=0: floor(v0)
    float* q = op + (size_t)k * TT * D;
#pragma unroll
    for (int r = 0; r < RPW; ++r) {
      s += (double)fmaxf(cur[r], 0.0f) * 0.001;
      const double fl = floor(v0 + s);
      q[(size_t)r * D] = (float)((fl - prev) * 1000.0);
      prev = fl;
    }
    sbase += acc;
  };

  for (int k = 0; k < NTILE; k += 2) {            // manual dbuf: no reg copies
    tile(k, bufA, bufB);
    tile(k + 1, bufB, bufA);
  }
}

extern "C" void kernel_launch(void* const* d_in, const int* in_sizes, int n_in,
                              void* d_out, int out_size, void* d_ws, size_t ws_size,
                              hipStream_t stream) {
  const float* in = (const float*)d_in[0];     // [B, T, D] f32
  const float* st = (const float*)d_in[1];     // [B, D]    f32
  float* out = (float*)d_out;                  // [B, T, D] f32

  // 16384 chains / 64 per block = 256 blocks x 1024 threads (16 waves).
  dim3 grid(B * D / CPB);
  dim3 block(NW * 64);
  spike_scan_kernel<<<grid, block, 0, stream>>>(in, st, out);
}